// Round 15
// baseline (420.142 us; speedup 1.0000x reference)
//
#include <hip/hip_runtime.h>
#include <hip/hip_fp16.h>
#include <math.h>

#define N_NODES 100000
#define N_EDGES 1600000
#define EPRIME  (N_EDGES + N_NODES)
#define NEG_SLOPE 0.2f
#define LOG2E 1.44269504f

typedef _Float16 f16x8 __attribute__((ext_vector_type(8)));
typedef float f32x4 __attribute__((ext_vector_type(4)));
typedef float f32x8 __attribute__((ext_vector_type(8)));
typedef float f32x16 __attribute__((ext_vector_type(16)));

__device__ __forceinline__ f32x8 unpack8(float4 r) {
    f32x8 o;
    float2 f;
    f = __half22float2(__builtin_bit_cast(__half2, r.x)); o[0] = f.x; o[1] = f.y;
    f = __half22float2(__builtin_bit_cast(__half2, r.y)); o[2] = f.x; o[3] = f.y;
    f = __half22float2(__builtin_bit_cast(__half2, r.z)); o[4] = f.x; o[5] = f.y;
    f = __half22float2(__builtin_bit_cast(__half2, r.w)); o[6] = f.x; o[7] = f.y;
    return o;
}

// dot of unpacked xi (8 ch) with packed fp16x8 fragment, no persistent unpack regs
__device__ __forceinline__ float dot8h(const f32x8& xi, float4 r, float d) {
    float2 f;
    f = __half22float2(__builtin_bit_cast(__half2, r.x)); d = fmaf(xi[0], f.x, d); d = fmaf(xi[1], f.y, d);
    f = __half22float2(__builtin_bit_cast(__half2, r.y)); d = fmaf(xi[2], f.x, d); d = fmaf(xi[3], f.y, d);
    f = __half22float2(__builtin_bit_cast(__half2, r.z)); d = fmaf(xi[4], f.x, d); d = fmaf(xi[5], f.y, d);
    f = __half22float2(__builtin_bit_cast(__half2, r.w)); d = fmaf(xi[6], f.x, d); d = fmaf(xi[7], f.y, d);
    return d;
}

// acc[BASE..BASE+7] += p * unpack(r); BASE is template-constant (rule-#20 safe)
template <int BASE>
__device__ __forceinline__ void acc8h(f32x16& acc, float p, float4 r) {
    float2 f;
    f = __half22float2(__builtin_bit_cast(__half2, r.x));
    acc[BASE + 0] = fmaf(p, f.x, acc[BASE + 0]); acc[BASE + 1] = fmaf(p, f.y, acc[BASE + 1]);
    f = __half22float2(__builtin_bit_cast(__half2, r.y));
    acc[BASE + 2] = fmaf(p, f.x, acc[BASE + 2]); acc[BASE + 3] = fmaf(p, f.y, acc[BASE + 3]);
    f = __half22float2(__builtin_bit_cast(__half2, r.z));
    acc[BASE + 4] = fmaf(p, f.x, acc[BASE + 4]); acc[BASE + 5] = fmaf(p, f.y, acc[BASE + 5]);
    f = __half22float2(__builtin_bit_cast(__half2, r.w));
    acc[BASE + 6] = fmaf(p, f.x, acc[BASE + 6]); acc[BASE + 7] = fmaf(p, f.y, acc[BASE + 7]);
}

// ---------------- edge dtype detect (int64 vs int32) ----------------
__global__ __launch_bounds__(256) void detect_k(const unsigned* __restrict__ w,
                                                unsigned* __restrict__ flag) {
    __shared__ int any;
    if (threadIdx.x == 0) any = 0;
    __syncthreads();
    int nz = 0;
    for (int i = threadIdx.x; i < 1024; i += 256)
        if (w[2 * i + 1] != 0u) nz = 1;
    if (nz) atomicOr(&any, 1);
    __syncthreads();
    if (threadIdx.x == 0) flag[0] = any ? 0u : 1u;  // 1 => int64
}

// ---------------- CSR build ----------------
__global__ __launch_bounds__(256) void init_k(int* __restrict__ counts) {
    int n = blockIdx.x * blockDim.x + threadIdx.x;
    if (n < N_NODES) counts[n] = 1;  // slot 0 of each row = self loop
}

__global__ __launch_bounds__(256) void countrank_k(const int* __restrict__ ei,
                                                   const unsigned* __restrict__ flag,
                                                   int* __restrict__ counts,
                                                   int* __restrict__ rank) {
    int e = blockIdx.x * blockDim.x + threadIdx.x;
    if (e >= N_EDGES) return;
    int d = flag[0] ? ei[2 * (N_EDGES + e)] : ei[N_EDGES + e];
    rank[e] = atomicAdd(&counts[d], 1);
}

// exclusive scan of counts[0..N-1] -> rowptr[0..N], 1024 elems/block
__global__ __launch_bounds__(256) void scan1_k(const int* __restrict__ counts,
                                               int* __restrict__ rowptr,
                                               int* __restrict__ bsums) {
    __shared__ int s[256];
    int t = threadIdx.x;
    int base = blockIdx.x * 1024 + t * 4;
    int v[4];
#pragma unroll
    for (int j = 0; j < 4; ++j)
        v[j] = (base + j < N_NODES) ? counts[base + j] : 0;
    int tsum = v[0] + v[1] + v[2] + v[3];
    s[t] = tsum;
    __syncthreads();
    for (int off = 1; off < 256; off <<= 1) {
        int x = (t >= off) ? s[t - off] : 0;
        __syncthreads();
        s[t] += x;
        __syncthreads();
    }
    if (t == 255) bsums[blockIdx.x] = s[255];
    int run = s[t] - tsum;  // exclusive prefix for this thread (block-local)
#pragma unroll
    for (int j = 0; j < 4; ++j) {
        if (base + j <= N_NODES) rowptr[base + j] = run;
        run += v[j];
    }
}

__global__ void scan2_k(int* __restrict__ bsums, int nb) {
    if (threadIdx.x == 0 && blockIdx.x == 0) {
        int run = 0;
        for (int i = 0; i < nb; ++i) { int c = bsums[i]; bsums[i] = run; run += c; }
    }
}

__global__ __launch_bounds__(256) void scan3_k(int* __restrict__ rowptr,
                                               const int* __restrict__ bsums) {
    int t = threadIdx.x;
    int base = blockIdx.x * 1024 + t * 4;
    int add = bsums[blockIdx.x];
#pragma unroll
    for (int j = 0; j < 4; ++j)
        if (base + j <= N_NODES) rowptr[base + j] += add;
}

// self loops (slot 0 of each row) + sentinel pad
__global__ __launch_bounds__(256) void selfloop_k(const int* __restrict__ rowptr,
                                                  int* __restrict__ col) {
    int n = blockIdx.x * blockDim.x + threadIdx.x;
    if (n < 8) col[EPRIME + n] = 0;
    if (n < N_NODES) col[rowptr[n]] = n;
}

// XCD-partitioned, atomic-free scatter (R13: col write amplification 16x -> 1x)
#define SCHUNK 2048
__global__ __launch_bounds__(256) void scatter2_k(const int* __restrict__ ei,
                                                  const unsigned* __restrict__ flag,
                                                  const int* __restrict__ rowptr,
                                                  const int* __restrict__ rank,
                                                  int* __restrict__ col) {
    int xcd = blockIdx.x & 7;
    int base = (blockIdx.x >> 3) * SCHUNK;
    int lo = xcd * 12500, hi = lo + 12500;
    int lim = min(base + SCHUNK, N_EDGES);
    bool f = flag[0] != 0;
    for (int i = base + threadIdx.x; i < lim; i += 256) {
        int d = f ? ei[2 * (N_EDGES + i)] : ei[N_EDGES + i];
        if (d >= lo && d < hi) {
            int s = f ? ei[2 * i] : ei[i];
            col[rowptr[d] + rank[i]] = s;
        }
    }
}

// ---------------- degree-sorted node permutation (two-level counting sort) ----------
__global__ void hzero_k(int* __restrict__ dbins) {
    if (blockIdx.x == 0) dbins[threadIdx.x] = 0;
}

__global__ __launch_bounds__(256) void hist_k(const int* __restrict__ counts,
                                              int* __restrict__ dbins) {
    __shared__ int lh[256];
    lh[threadIdx.x] = 0;
    __syncthreads();
    int n = blockIdx.x * 256 + threadIdx.x;
    if (n < N_NODES) atomicAdd(&lh[min(counts[n], 255)], 1);
    __syncthreads();
    int c = lh[threadIdx.x];
    if (c) atomicAdd(&dbins[threadIdx.x], c);
}

__global__ __launch_bounds__(256) void hscan_k(const int* __restrict__ dbins,
                                               int* __restrict__ dstart,
                                               int* __restrict__ dfill) {
    __shared__ int s[256];
    int t = threadIdx.x;
    int v = dbins[t];
    s[t] = v;
    __syncthreads();
    for (int off = 1; off < 256; off <<= 1) {
        int x = (t >= off) ? s[t - off] : 0;
        __syncthreads();
        s[t] += x;
        __syncthreads();
    }
    dstart[t] = s[t] - v;  // exclusive
    dfill[t] = 0;
}

__global__ __launch_bounds__(256) void hscatter_k(const int* __restrict__ counts,
                                                  const int* __restrict__ dstart,
                                                  int* __restrict__ dfill,
                                                  int* __restrict__ perm) {
    __shared__ int lh[256];
    __shared__ int lbase[256];
    lh[threadIdx.x] = 0;
    __syncthreads();
    int n = blockIdx.x * 256 + threadIdx.x;
    int b = 0, lrank = 0;
    bool valid = n < N_NODES;
    if (valid) {
        b = min(counts[n], 255);
        lrank = atomicAdd(&lh[b], 1);   // LDS atomic: within-block rank
    }
    __syncthreads();
    int c = lh[threadIdx.x];
    lbase[threadIdx.x] = c ? atomicAdd(&dfill[threadIdx.x], c) : 0;  // 1 global atomic/bin/block
    __syncthreads();
    if (valid) perm[dstart[b] + lbase[b] + lrank] = n;
}

// ---------------- W1 -> fp16 fragment-order pre-swizzle ----------------
__global__ __launch_bounds__(256) void w1cvt_k(const float* __restrict__ W1,
                                               _Float16* __restrict__ W1f) {
    int idx = blockIdx.x * 256 + threadIdx.x;
    if (idx >= 512 * 64) return;
    int j    = idx & 7;
    int lane = (idx >> 3) & 63;
    int nt   = (idx >> 9) & 3;
    int ks   = idx >> 11;
    int k = ks * 32 + (lane >> 4) * 8 + j;
    int c = nt * 16 + (lane & 15);
    W1f[idx] = (_Float16)W1[k * 64 + c];
}

// ---------------- GEMM1 (MFMA): h1 = x @ W1, h1 fp16 + fused att dots --------
__global__ __launch_bounds__(256) void gemm1_k(const float* __restrict__ x,
                                               const _Float16* __restrict__ W1f,
                                               const float* __restrict__ attl,
                                               const float* __restrict__ attr,
                                               __half* __restrict__ h1,
                                               float* __restrict__ ald,
                                               float* __restrict__ ard) {
    int t = threadIdx.x;
    int w = t >> 6, l = t & 63;
    int rw0 = blockIdx.x * 64 + w * 16;
    int arow = rw0 + (l & 15);
    if (arow >= N_NODES) arow = N_NODES - 1;  // clamp; OOB outputs are guarded
    int kg = l >> 4;                           // k-group 0..3
    const float4* x4 = (const float4*)(x + (size_t)arow * 512);
    const f16x8* w8 = (const f16x8*)W1f;

    f32x4 acc0 = {0.f, 0.f, 0.f, 0.f};
    f32x4 acc1 = {0.f, 0.f, 0.f, 0.f};
    f32x4 acc2 = {0.f, 0.f, 0.f, 0.f};
    f32x4 acc3 = {0.f, 0.f, 0.f, 0.f};

#pragma unroll 4
    for (int ks = 0; ks < 16; ++ks) {
        float4 a0 = x4[ks * 8 + kg * 2];
        float4 a1 = x4[ks * 8 + kg * 2 + 1];
        f16x8 af;
        af[0] = (_Float16)a0.x; af[1] = (_Float16)a0.y;
        af[2] = (_Float16)a0.z; af[3] = (_Float16)a0.w;
        af[4] = (_Float16)a1.x; af[5] = (_Float16)a1.y;
        af[6] = (_Float16)a1.z; af[7] = (_Float16)a1.w;
        f16x8 b0 = w8[(ks * 4 + 0) * 64 + l];
        f16x8 b1 = w8[(ks * 4 + 1) * 64 + l];
        f16x8 b2 = w8[(ks * 4 + 2) * 64 + l];
        f16x8 b3 = w8[(ks * 4 + 3) * 64 + l];
        acc0 = __builtin_amdgcn_mfma_f32_16x16x32_f16(af, b0, acc0, 0, 0, 0);
        acc1 = __builtin_amdgcn_mfma_f32_16x16x32_f16(af, b1, acc1, 0, 0, 0);
        acc2 = __builtin_amdgcn_mfma_f32_16x16x32_f16(af, b2, acc2, 0, 0, 0);
        acc3 = __builtin_amdgcn_mfma_f32_16x16x32_f16(af, b3, acc3, 0, 0, 0);
    }

    int col = l & 15;
    int hi = col >> 3;
    float al0 = attl[col], al1 = attl[16 + col], al2 = attl[32 + col], al3 = attl[48 + col];
    float ar0 = attr[col], ar1 = attr[16 + col], ar2 = attr[32 + col], ar3 = attr[48 + col];

#pragma unroll
    for (int reg = 0; reg < 4; ++reg) {
        int grow = rw0 + (l >> 4) * 4 + reg;
        bool v = grow < N_NODES;
        float c0 = acc0[reg], c1 = acc1[reg], c2 = acc2[reg], c3 = acc3[reg];
        if (v) {
            __half* hp = h1 + (size_t)grow * 64;
            hp[col]      = __float2half_rn(c0);
            hp[16 + col] = __float2half_rn(c1);
            hp[32 + col] = __float2half_rn(c2);
            hp[48 + col] = __float2half_rn(c3);
        }
        float vl0 = c0 * al0, vl1 = c1 * al1, vl2 = c2 * al2, vl3 = c3 * al3;
        float vr0 = c0 * ar0, vr1 = c1 * ar1, vr2 = c2 * ar2, vr3 = c3 * ar3;
        vl0 += __shfl_xor(vl0, 1); vl1 += __shfl_xor(vl1, 1);
        vl2 += __shfl_xor(vl2, 1); vl3 += __shfl_xor(vl3, 1);
        vr0 += __shfl_xor(vr0, 1); vr1 += __shfl_xor(vr1, 1);
        vr2 += __shfl_xor(vr2, 1); vr3 += __shfl_xor(vr3, 1);
        vl0 += __shfl_xor(vl0, 2); vl1 += __shfl_xor(vl1, 2);
        vl2 += __shfl_xor(vl2, 2); vl3 += __shfl_xor(vl3, 2);
        vr0 += __shfl_xor(vr0, 2); vr1 += __shfl_xor(vr1, 2);
        vr2 += __shfl_xor(vr2, 2); vr3 += __shfl_xor(vr3, 2);
        vl0 += __shfl_xor(vl0, 4); vl1 += __shfl_xor(vl1, 4);
        vl2 += __shfl_xor(vl2, 4); vl3 += __shfl_xor(vl3, 4);
        vr0 += __shfl_xor(vr0, 4); vr1 += __shfl_xor(vr1, 4);
        vr2 += __shfl_xor(vr2, 4); vr3 += __shfl_xor(vr3, 4);
        if (v && (l & 7) == 0) {
            float* alp = ald + (size_t)grow * 8;
            float* arp = ard + (size_t)grow * 8;
            alp[0 + hi] = vl0 * LOG2E; alp[2 + hi] = vl1 * LOG2E;
            alp[4 + hi] = vl2 * LOG2E; alp[6 + hi] = vl3 * LOG2E;
            arp[0 + hi] = vr0 * LOG2E; arp[2 + hi] = vr1 * LOG2E;
            arp[4 + hi] = vr2 * LOG2E; arp[6 + hi] = vr3 * LOG2E;
        }
    }
}

// ---------------- attn1 v3 (unchanged control): lane = (node, head), 2-deep ---------
__global__ __launch_bounds__(256) void attn1_k(const __half* __restrict__ h1,
                                               const int* __restrict__ rowptr,
                                               const int* __restrict__ col,
                                               const float* __restrict__ ald,
                                               const float* __restrict__ ard,
                                               const float* __restrict__ b1,
                                               const int* __restrict__ perm,
                                               float* __restrict__ hout) {
    int gid = (blockIdx.x * 256 + threadIdx.x) >> 3;
    int h = threadIdx.x & 7;
    if (gid >= N_NODES) return;
    int node = perm[gid];
    const char* hb = (const char*)h1;
    unsigned hoff = (unsigned)h * 16u;

    f32x8 xi = unpack8(*(const float4*)(hb + (unsigned)node * 128u + hoff));
    float ardi = ard[node * 8 + h];
    int beg = rowptr[node], end = rowptr[node + 1];

    int s0 = col[beg], s1 = col[beg + 1];
    float4 rx0 = *(const float4*)(hb + (unsigned)s0 * 128u + hoff);
    float aj0 = ald[s0 * 8 + h];
    float4 rx1 = *(const float4*)(hb + (unsigned)s1 * 128u + hoff);
    float aj1 = ald[s1 * 8 + h];

    float m2 = -INFINITY, lsum = 0.f;
    f32x8 acc = {0.f, 0.f, 0.f, 0.f, 0.f, 0.f, 0.f, 0.f};
    for (int e = beg; e < end; e += 2) {
        int t0 = col[e + 2], t1 = col[e + 3];
        float4 ry0 = *(const float4*)(hb + (unsigned)t0 * 128u + hoff);
        float c0 = ald[t0 * 8 + h];
        float4 ry1 = *(const float4*)(hb + (unsigned)t1 * 128u + hoff);
        float c1 = ald[t1 * 8 + h];

        f32x8 xj0 = unpack8(rx0);
        f32x8 xj1 = unpack8(rx1);
        float d0 = 0.f, d1 = 0.f;
#pragma unroll
        for (int c = 0; c < 8; ++c) { d0 = fmaf(xi[c], xj0[c], d0); d1 = fmaf(xi[c], xj1[c], d1); }
        float g0 = (aj0 + ardi) * __builtin_amdgcn_rcpf(1.f + __builtin_amdgcn_exp2f(d0 * -LOG2E));
        float g1 = (aj1 + ardi) * __builtin_amdgcn_rcpf(1.f + __builtin_amdgcn_exp2f(d1 * -LOG2E));
        float a0 = fmaxf(g0, NEG_SLOPE * g0);
        float a1 = (e + 1 < end) ? fmaxf(g1, NEG_SLOPE * g1) : -INFINITY;
        float pm = fmaxf(a0, a1);
        if (__any(pm > m2 + 11.5f)) {
            float mn = fmaxf(m2, pm);
            float so = __builtin_amdgcn_exp2f(m2 - mn);
            lsum *= so;
#pragma unroll
            for (int c = 0; c < 8; ++c) acc[c] *= so;
            m2 = mn;
        }
        float p0 = __builtin_amdgcn_exp2f(a0 - m2);
        float p1 = __builtin_amdgcn_exp2f(a1 - m2);
        lsum += p0 + p1;
#pragma unroll
        for (int c = 0; c < 8; ++c) acc[c] += p0 * xj0[c] + p1 * xj1[c];
        rx0 = ry0; aj0 = c0; rx1 = ry1; aj1 = c1;
    }
    float rl = __builtin_amdgcn_rcpf(lsum);
    float4 bv0 = *(const float4*)(b1 + h * 8);
    float4 bv1 = *(const float4*)(b1 + h * 8 + 4);
    float ob[8];
    ob[0] = bv0.x; ob[1] = bv0.y; ob[2] = bv0.z; ob[3] = bv0.w;
    ob[4] = bv1.x; ob[5] = bv1.y; ob[6] = bv1.z; ob[7] = bv1.w;
    float4 o0, o1;
    float* op0 = (float*)&o0;
    float* op1 = (float*)&o1;
#pragma unroll
    for (int c = 0; c < 8; ++c) {
        float o = acc[c] * rl + ob[c];
        o = o > 0.f ? o : (__builtin_amdgcn_exp2f(o * LOG2E) - 1.f);  // ELU
        if (c < 4) op0[c] = o; else op1[c - 4] = o;
    }
    float4* dst = (float4*)(hout + (size_t)node * 64 + h * 8);
    dst[0] = o0;
    dst[1] = o1;
}

// ---------------- GEMM2: h2 = hout @ W2  (N x 64) @ (64 x 128), h2 stored fp16x2 ------
__global__ __launch_bounds__(256) void gemm2_k(const float* __restrict__ h,
                                               const float* __restrict__ W2,
                                               const float* __restrict__ attl,
                                               const float* __restrict__ attr,
                                               __half2* __restrict__ h2,
                                               float* __restrict__ ald,
                                               float* __restrict__ ard) {
    __shared__ float xs[32 * 64];
    int t = threadIdx.x;
    int row0 = blockIdx.x * 32;
    for (int i = t; i < 32 * 16; i += 256) {
        int r = i >> 4, q = i & 15;
        int gr = row0 + r;
        float4 v = make_float4(0.f, 0.f, 0.f, 0.f);
        if (gr < N_NODES) v = ((const float4*)h)[(size_t)gr * 16 + q];
        ((float4*)xs)[r * 16 + q] = v;
    }
    __syncthreads();
    int w = t >> 6, lane = t & 63;
    int r0 = w * 8;
    float2 acc[8];
#pragma unroll
    for (int r = 0; r < 8; ++r) acc[r] = make_float2(0.f, 0.f);
    for (int k = 0; k < 64; ++k) {
        float2 wv = ((const float2*)W2)[k * 64 + lane];
#pragma unroll
        for (int r = 0; r < 8; ++r) {
            float xv = xs[(r0 + r) * 64 + k];
            acc[r].x += xv * wv.x;
            acc[r].y += xv * wv.y;
        }
    }
    float2 al = ((const float2*)attl)[lane];
    float2 ar = ((const float2*)attr)[lane];
#pragma unroll
    for (int r = 0; r < 8; ++r) {
        int gr = row0 + r0 + r;
        float vl = acc[r].x * al.x + acc[r].y * al.y;
        float vr = acc[r].x * ar.x + acc[r].y * ar.y;
        vl += __shfl_xor(vl, 1); vr += __shfl_xor(vr, 1);
        vl += __shfl_xor(vl, 2); vr += __shfl_xor(vr, 2);
        vl += __shfl_xor(vl, 4); vr += __shfl_xor(vr, 4);
        if (gr < N_NODES) {
            h2[(size_t)gr * 64 + lane] = __floats2half2_rn(acc[r].x, acc[r].y);
            if ((lane & 7) == 0) {
                ald[gr * 8 + (lane >> 3)] = vl * LOG2E;
                ard[gr * 8 + (lane >> 3)] = vr * LOG2E;
            }
        }
    }
}

// ---------------- attn2 v4: lane = (node, head); 16 ch/lane; 4-deep edge pipeline ---
// R14 change: 2->4 deep MLP (the gather chain is latency-bound; occupancy bin
// 65-128 VGPR unchanged). Packed fragments consumed via cvt+fma helpers so no
// persistent unpacked state (keeps VGPR < 128).
__global__ __launch_bounds__(256) void attn2_k(const __half* __restrict__ h2,
                                               const int* __restrict__ rowptr,
                                               const int* __restrict__ col,
                                               const float* __restrict__ ald,
                                               const float* __restrict__ ard,
                                               const float* __restrict__ b2,
                                               const int* __restrict__ perm,
                                               float* __restrict__ out) {
    int gid = (blockIdx.x * 256 + threadIdx.x) >> 3;
    int h = threadIdx.x & 7;
    if (gid >= N_NODES) return;
    int node = perm[gid];
    const char* hb = (const char*)h2;
    unsigned hoff = (unsigned)h * 32u;

    f32x8 xiA = unpack8(*(const float4*)(hb + (unsigned)node * 256u + hoff));
    f32x8 xiB = unpack8(*(const float4*)(hb + (unsigned)node * 256u + hoff + 16u));
    float ardi = ard[node * 8 + h];
    int beg = rowptr[node], end = rowptr[node + 1];

    int s0 = col[beg], s1 = col[beg + 1], s2 = col[beg + 2], s3 = col[beg + 3];
    float4 r0a = *(const float4*)(hb + (unsigned)s0 * 256u + hoff);
    float4 r0b = *(const float4*)(hb + (unsigned)s0 * 256u + hoff + 16u);
    float aj0 = ald[s0 * 8 + h];
    float4 r1a = *(const float4*)(hb + (unsigned)s1 * 256u + hoff);
    float4 r1b = *(const float4*)(hb + (unsigned)s1 * 256u + hoff + 16u);
    float aj1 = ald[s1 * 8 + h];
    float4 r2a = *(const float4*)(hb + (unsigned)s2 * 256u + hoff);
    float4 r2b = *(const float4*)(hb + (unsigned)s2 * 256u + hoff + 16u);
    float aj2 = ald[s2 * 8 + h];
    float4 r3a = *(const float4*)(hb + (unsigned)s3 * 256u + hoff);
    float4 r3b = *(const float4*)(hb + (unsigned)s3 * 256u + hoff + 16u);
    float aj3 = ald[s3 * 8 + h];

    float m2 = -INFINITY, lsum = 0.f;
    f32x16 acc;
#pragma unroll
    for (int c = 0; c < 16; ++c) acc[c] = 0.f;

    for (int e = beg; e < end; e += 4) {
        int t0 = col[e + 4], t1 = col[e + 5], t2 = col[e + 6], t3 = col[e + 7];
        float4 y0a = *(const float4*)(hb + (unsigned)t0 * 256u + hoff);
        float4 y0b = *(const float4*)(hb + (unsigned)t0 * 256u + hoff + 16u);
        float c0 = ald[t0 * 8 + h];
        float4 y1a = *(const float4*)(hb + (unsigned)t1 * 256u + hoff);
        float4 y1b = *(const float4*)(hb + (unsigned)t1 * 256u + hoff + 16u);
        float c1 = ald[t1 * 8 + h];
        float4 y2a = *(const float4*)(hb + (unsigned)t2 * 256u + hoff);
        float4 y2b = *(const float4*)(hb + (unsigned)t2 * 256u + hoff + 16u);
        float c2 = ald[t2 * 8 + h];
        float4 y3a = *(const float4*)(hb + (unsigned)t3 * 256u + hoff);
        float4 y3b = *(const float4*)(hb + (unsigned)t3 * 256u + hoff + 16u);
        float c3 = ald[t3 * 8 + h];

        float d0 = dot8h(xiB, r0b, dot8h(xiA, r0a, 0.f));
        float d1 = dot8h(xiB, r1b, dot8h(xiA, r1a, 0.f));
        float d2 = dot8h(xiB, r2b, dot8h(xiA, r2a, 0.f));
        float d3 = dot8h(xiB, r3b, dot8h(xiA, r3a, 0.f));
        float g0 = (aj0 + ardi) * __builtin_amdgcn_rcpf(1.f + __builtin_amdgcn_exp2f(d0 * -LOG2E));
        float g1 = (aj1 + ardi) * __builtin_amdgcn_rcpf(1.f + __builtin_amdgcn_exp2f(d1 * -LOG2E));
        float g2 = (aj2 + ardi) * __builtin_amdgcn_rcpf(1.f + __builtin_amdgcn_exp2f(d2 * -LOG2E));
        float g3 = (aj3 + ardi) * __builtin_amdgcn_rcpf(1.f + __builtin_amdgcn_exp2f(d3 * -LOG2E));
        float a0 = fmaxf(g0, NEG_SLOPE * g0);
        float a1 = (e + 1 < end) ? fmaxf(g1, NEG_SLOPE * g1) : -INFINITY;
        float a2 = (e + 2 < end) ? fmaxf(g2, NEG_SLOPE * g2) : -INFINITY;
        float a3 = (e + 3 < end) ? fmaxf(g3, NEG_SLOPE * g3) : -INFINITY;
        float pm = fmaxf(fmaxf(a0, a1), fmaxf(a2, a3));
        if (__any(pm > m2 + 11.5f)) {
            float mn = fmaxf(m2, pm);
            float so = __builtin_amdgcn_exp2f(m2 - mn);
            lsum *= so;
#pragma unroll
            for (int c = 0; c < 16; ++c) acc[c] *= so;
            m2 = mn;
        }
        float p0 = __builtin_amdgcn_exp2f(a0 - m2);
        float p1 = __builtin_amdgcn_exp2f(a1 - m2);
        float p2 = __builtin_amdgcn_exp2f(a2 - m2);
        float p3 = __builtin_amdgcn_exp2f(a3 - m2);
        lsum += (p0 + p1) + (p2 + p3);
        acc8h<0>(acc, p0, r0a); acc8h<8>(acc, p0, r0b);
        acc8h<0>(acc, p1, r1a); acc8h<8>(acc, p1, r1b);
        acc8h<0>(acc, p2, r2a); acc8h<8>(acc, p2, r2b);
        acc8h<0>(acc, p3, r3a); acc8h<8>(acc, p3, r3b);
        r0a = y0a; r0b = y0b; aj0 = c0;
        r1a = y1a; r1b = y1b; aj1 = c1;
        r2a = y2a; r2b = y2b; aj2 = c2;
        r3a = y3a; r3b = y3b; aj3 = c3;
    }

    float rl = __builtin_amdgcn_rcpf(lsum);
    f32x16 v;
#pragma unroll
    for (int c = 0; c < 16; ++c) v[c] = acc[c] * rl;
#pragma unroll
    for (int c = 0; c < 16; ++c) {
        v[c] += __shfl_xor(v[c], 1);
        v[c] += __shfl_xor(v[c], 2);
        v[c] += __shfl_xor(v[c], 4);
    }
    float mx = -INFINITY;
#pragma unroll
    for (int c = 0; c < 16; ++c) { v[c] = v[c] * 0.125f + b2[c]; mx = fmaxf(mx, v[c]); }
    float se = 0.f;
#pragma unroll
    for (int c = 0; c < 16; ++c) se += __expf(v[c] - mx);
    float ls = __logf(se);
    if (h == 0) {
        float4 o;
        float* op = (float*)&o;
        float* dst = out + (size_t)node * 16;
#pragma unroll
        for (int q = 0; q < 4; ++q) {
#pragma unroll
            for (int c = 0; c < 4; ++c) op[c] = v[q * 4 + c] - mx - ls;
            ((float4*)dst)[q] = o;
        }
    }
}

// ---------------- host ----------------
extern "C" void kernel_launch(void* const* d_in, const int* in_sizes, int n_in,
                              void* d_out, int out_size, void* d_ws, size_t ws_size,
                              hipStream_t stream) {
    const float* x     = (const float*)d_in[0];
    const int*   ei    = (const int*)d_in[1];
    const float* W1    = (const float*)d_in[2];
    const float* attl1 = (const float*)d_in[3];
    const float* attr1 = (const float*)d_in[4];
    const float* b1    = (const float*)d_in[5];
    const float* W2    = (const float*)d_in[6];
    const float* attl2 = (const float*)d_in[7];
    const float* attr2 = (const float*)d_in[8];
    const float* b2    = (const float*)d_in[9];
    float* out = (float*)d_out;

    char* ws = (char*)d_ws;
    size_t off = 0;
    auto alloc = [&](size_t bytes) {
        size_t o = off;
        off += (bytes + 255) & ~(size_t)255;
        return o;
    };
    size_t o_flag   = alloc(4);
    size_t o_counts = alloc((size_t)N_NODES * 4);
    size_t o_rank   = alloc((size_t)N_EDGES * 4);
    size_t o_rowptr = alloc((size_t)(N_NODES + 1) * 4);
    size_t o_bsums  = alloc(1024 * 4);
    size_t o_col    = alloc((size_t)(EPRIME + 8) * 4);   // +8 sentinel pad
    size_t o_h1     = alloc((size_t)N_NODES * 64 * 4);   // (over-alloc; h1 is fp16)
    size_t o_hout   = alloc((size_t)N_NODES * 64 * 4);
    size_t o_h2     = alloc((size_t)N_NODES * 128 * 4);  // (over-alloc; h2 is fp16)
    size_t o_w1f    = alloc((size_t)512 * 64 * 2);       // fp16 swizzled W1
    size_t o_perm   = alloc((size_t)N_NODES * 4);
    size_t o_dbins  = alloc(256 * 4);
    size_t o_dstart = alloc(256 * 4);
    size_t o_dfill  = alloc(256 * 4);

    size_t aldsz = ((size_t)N_NODES * 8 * 4 + 255) & ~(size_t)255;
    size_t o_ald1 = o_h2;
    size_t o_ard1 = o_h2 + aldsz;
    size_t o_ald2 = o_h1;
    size_t o_ard2 = o_h1 + aldsz;

    unsigned* flag = (unsigned*)(ws + o_flag);
    int* counts = (int*)(ws + o_counts);
    int* rank   = (int*)(ws + o_rank);
    int* rowptr = (int*)(ws + o_rowptr);
    int* bsums  = (int*)(ws + o_bsums);
    int* col    = (int*)(ws + o_col);
    __half* h1  = (__half*)(ws + o_h1);
    float* hout = (float*)(ws + o_hout);
    __half* h2  = (__half*)(ws + o_h2);
    _Float16* w1f = (_Float16*)(ws + o_w1f);
    int* perm   = (int*)(ws + o_perm);
    int* dbins  = (int*)(ws + o_dbins);
    int* dstart = (int*)(ws + o_dstart);
    int* dfill  = (int*)(ws + o_dfill);
    float* ald1 = (float*)(ws + o_ald1);
    float* ard1 = (float*)(ws + o_ard1);
    float* ald2 = (float*)(ws + o_ald2);
    float* ard2 = (float*)(ws + o_ard2);

    int nscan = (N_NODES + 1 + 1023) / 1024;  // 99
    int nblk  = (N_NODES + 255) / 256;
    int nscat = 8 * ((N_EDGES + SCHUNK - 1) / SCHUNK);

    hipLaunchKernelGGL(detect_k, dim3(1), dim3(256), 0, stream, (const unsigned*)ei, flag);
    hipLaunchKernelGGL(init_k, dim3(nblk), dim3(256), 0, stream, counts);
    hipLaunchKernelGGL(countrank_k, dim3((N_EDGES + 255) / 256), dim3(256), 0, stream,
                       ei, flag, counts, rank);
    // degree-sorted permutation (two-level counting sort over 256 degree bins)
    hipLaunchKernelGGL(hzero_k, dim3(1), dim3(256), 0, stream, dbins);
    hipLaunchKernelGGL(hist_k, dim3(nblk), dim3(256), 0, stream, counts, dbins);
    hipLaunchKernelGGL(hscan_k, dim3(1), dim3(256), 0, stream, dbins, dstart, dfill);
    hipLaunchKernelGGL(hscatter_k, dim3(nblk), dim3(256), 0, stream, counts, dstart, dfill, perm);
    hipLaunchKernelGGL(scan1_k, dim3(nscan), dim3(256), 0, stream, counts, rowptr, bsums);
    hipLaunchKernelGGL(scan2_k, dim3(1), dim3(64), 0, stream, bsums, nscan);
    hipLaunchKernelGGL(scan3_k, dim3(nscan), dim3(256), 0, stream, rowptr, bsums);
    hipLaunchKernelGGL(selfloop_k, dim3(nblk), dim3(256), 0, stream, rowptr, col);
    hipLaunchKernelGGL(scatter2_k, dim3(nscat), dim3(256), 0, stream,
                       ei, flag, rowptr, rank, col);
    hipLaunchKernelGGL(w1cvt_k, dim3(128), dim3(256), 0, stream, W1, w1f);
    hipLaunchKernelGGL(gemm1_k, dim3((N_NODES + 63) / 64), dim3(256), 0, stream,
                       x, w1f, attl1, attr1, h1, ald1, ard1);
    hipLaunchKernelGGL(attn1_k, dim3((N_NODES * 8 + 255) / 256), dim3(256), 0, stream,
                       h1, rowptr, col, ald1, ard1, b1, perm, hout);
    hipLaunchKernelGGL(gemm2_k, dim3((N_NODES + 31) / 32), dim3(256), 0, stream,
                       hout, W2, attl2, attr2, (__half2*)h2, ald2, ard2);
    hipLaunchKernelGGL(attn2_k, dim3((N_NODES * 8 + 255) / 256), dim3(256), 0, stream,
                       h2, rowptr, col, ald2, ard2, b2, perm, out);
}

// Round 16
// 394.623 us; speedup vs baseline: 1.0647x; 1.0647x over previous
//
#include <hip/hip_runtime.h>
#include <hip/hip_fp16.h>
#include <math.h>

#define N_NODES 100000
#define N_EDGES 1600000
#define EPRIME  (N_EDGES + N_NODES)
#define NEG_SLOPE 0.2f
#define LOG2E 1.44269504f

typedef _Float16 f16x8 __attribute__((ext_vector_type(8)));
typedef float f32x4 __attribute__((ext_vector_type(4)));
typedef float f32x8 __attribute__((ext_vector_type(8)));
typedef float f32x16 __attribute__((ext_vector_type(16)));

__device__ __forceinline__ f32x8 unpack8(float4 r) {
    f32x8 o;
    float2 f;
    f = __half22float2(__builtin_bit_cast(__half2, r.x)); o[0] = f.x; o[1] = f.y;
    f = __half22float2(__builtin_bit_cast(__half2, r.y)); o[2] = f.x; o[3] = f.y;
    f = __half22float2(__builtin_bit_cast(__half2, r.z)); o[4] = f.x; o[5] = f.y;
    f = __half22float2(__builtin_bit_cast(__half2, r.w)); o[6] = f.x; o[7] = f.y;
    return o;
}

// ---------------- edge dtype detect (int64 vs int32) ----------------
__global__ __launch_bounds__(256) void detect_k(const unsigned* __restrict__ w,
                                                unsigned* __restrict__ flag) {
    __shared__ int any;
    if (threadIdx.x == 0) any = 0;
    __syncthreads();
    int nz = 0;
    for (int i = threadIdx.x; i < 1024; i += 256)
        if (w[2 * i + 1] != 0u) nz = 1;
    if (nz) atomicOr(&any, 1);
    __syncthreads();
    if (threadIdx.x == 0) flag[0] = any ? 0u : 1u;  // 1 => int64
}

// ---------------- CSR build ----------------
// + fused dbins zeroing (was hzero_k)
__global__ __launch_bounds__(256) void init_k(int* __restrict__ counts,
                                              int* __restrict__ dbins) {
    int n = blockIdx.x * blockDim.x + threadIdx.x;
    if (n < N_NODES) counts[n] = 1;  // slot 0 of each row = self loop
    if (blockIdx.x == 0) dbins[threadIdx.x] = 0;
}

__global__ __launch_bounds__(256) void countrank_k(const int* __restrict__ ei,
                                                   const unsigned* __restrict__ flag,
                                                   int* __restrict__ counts,
                                                   int* __restrict__ rank) {
    int e = blockIdx.x * blockDim.x + threadIdx.x;
    if (e >= N_EDGES) return;
    int d = flag[0] ? ei[2 * (N_EDGES + e)] : ei[N_EDGES + e];
    rank[e] = atomicAdd(&counts[d], 1);
}

// exclusive scan of counts[0..N-1] -> rowptr[0..N], 1024 elems/block
__global__ __launch_bounds__(256) void scan1_k(const int* __restrict__ counts,
                                               int* __restrict__ rowptr,
                                               int* __restrict__ bsums) {
    __shared__ int s[256];
    int t = threadIdx.x;
    int base = blockIdx.x * 1024 + t * 4;
    int v[4];
#pragma unroll
    for (int j = 0; j < 4; ++j)
        v[j] = (base + j < N_NODES) ? counts[base + j] : 0;
    int tsum = v[0] + v[1] + v[2] + v[3];
    s[t] = tsum;
    __syncthreads();
    for (int off = 1; off < 256; off <<= 1) {
        int x = (t >= off) ? s[t - off] : 0;
        __syncthreads();
        s[t] += x;
        __syncthreads();
    }
    if (t == 255) bsums[blockIdx.x] = s[255];
    int run = s[t] - tsum;  // exclusive prefix for this thread (block-local)
#pragma unroll
    for (int j = 0; j < 4; ++j) {
        if (base + j <= N_NODES) rowptr[base + j] = run;
        run += v[j];
    }
}

// v2: computes its own bsums prefix (replaces serial scan2_k) and fuses the
// self-loop col writes + sentinel pad (replaces selfloop_k): final rowptr
// values are available right here.
__global__ __launch_bounds__(256) void scan3_k(int* __restrict__ rowptr,
                                               const int* __restrict__ bsums,
                                               int* __restrict__ col) {
    __shared__ int s[256];
    int t = threadIdx.x;
    int bid = blockIdx.x;
    s[t] = (t < bid) ? bsums[t] : 0;  // nscan=99 <= 256
    __syncthreads();
    for (int off = 128; off > 0; off >>= 1) {
        if (t < off) s[t] += s[t + off];
        __syncthreads();
    }
    int add = s[0];
    int base = bid * 1024 + t * 4;
#pragma unroll
    for (int j = 0; j < 4; ++j) {
        int idx = base + j;
        if (idx <= N_NODES) {
            int rv = rowptr[idx] + add;
            rowptr[idx] = rv;
            if (idx < N_NODES) col[rv] = idx;  // self loop at slot 0
        }
    }
    if (bid == 0 && t < 8) col[EPRIME + t] = 0;  // sentinel pad
}

// XCD-partitioned, atomic-free scatter (R13: col write amplification 16x -> 1x)
#define SCHUNK 2048
__global__ __launch_bounds__(256) void scatter2_k(const int* __restrict__ ei,
                                                  const unsigned* __restrict__ flag,
                                                  const int* __restrict__ rowptr,
                                                  const int* __restrict__ rank,
                                                  int* __restrict__ col) {
    int xcd = blockIdx.x & 7;
    int base = (blockIdx.x >> 3) * SCHUNK;
    int lo = xcd * 12500, hi = lo + 12500;
    int lim = min(base + SCHUNK, N_EDGES);
    bool f = flag[0] != 0;
    for (int i = base + threadIdx.x; i < lim; i += 256) {
        int d = f ? ei[2 * (N_EDGES + i)] : ei[N_EDGES + i];
        if (d >= lo && d < hi) {
            int s = f ? ei[2 * i] : ei[i];
            col[rowptr[d] + rank[i]] = s;
        }
    }
}

// ---------------- degree-sorted node permutation (two-level counting sort) ----------
__global__ __launch_bounds__(256) void hist_k(const int* __restrict__ counts,
                                              int* __restrict__ dbins) {
    __shared__ int lh[256];
    lh[threadIdx.x] = 0;
    __syncthreads();
    int n = blockIdx.x * 256 + threadIdx.x;
    if (n < N_NODES) atomicAdd(&lh[min(counts[n], 255)], 1);
    __syncthreads();
    int c = lh[threadIdx.x];
    if (c) atomicAdd(&dbins[threadIdx.x], c);
}

__global__ __launch_bounds__(256) void hscan_k(const int* __restrict__ dbins,
                                               int* __restrict__ dstart,
                                               int* __restrict__ dfill) {
    __shared__ int s[256];
    int t = threadIdx.x;
    int v = dbins[t];
    s[t] = v;
    __syncthreads();
    for (int off = 1; off < 256; off <<= 1) {
        int x = (t >= off) ? s[t - off] : 0;
        __syncthreads();
        s[t] += x;
        __syncthreads();
    }
    dstart[t] = s[t] - v;  // exclusive
    dfill[t] = 0;
}

__global__ __launch_bounds__(256) void hscatter_k(const int* __restrict__ counts,
                                                  const int* __restrict__ dstart,
                                                  int* __restrict__ dfill,
                                                  int* __restrict__ perm) {
    __shared__ int lh[256];
    __shared__ int lbase[256];
    lh[threadIdx.x] = 0;
    __syncthreads();
    int n = blockIdx.x * 256 + threadIdx.x;
    int b = 0, lrank = 0;
    bool valid = n < N_NODES;
    if (valid) {
        b = min(counts[n], 255);
        lrank = atomicAdd(&lh[b], 1);   // LDS atomic: within-block rank
    }
    __syncthreads();
    int c = lh[threadIdx.x];
    lbase[threadIdx.x] = c ? atomicAdd(&dfill[threadIdx.x], c) : 0;  // 1 global atomic/bin/block
    __syncthreads();
    if (valid) perm[dstart[b] + lbase[b] + lrank] = n;
}

// ---------------- W1 -> fp16 fragment-order pre-swizzle ----------------
__global__ __launch_bounds__(256) void w1cvt_k(const float* __restrict__ W1,
                                               _Float16* __restrict__ W1f) {
    int idx = blockIdx.x * 256 + threadIdx.x;
    if (idx >= 512 * 64) return;
    int j    = idx & 7;
    int lane = (idx >> 3) & 63;
    int nt   = (idx >> 9) & 3;
    int ks   = idx >> 11;
    int k = ks * 32 + (lane >> 4) * 8 + j;
    int c = nt * 16 + (lane & 15);
    W1f[idx] = (_Float16)W1[k * 64 + c];
}

// ---------------- GEMM1 (MFMA): h1 = x @ W1, h1 fp16 + fused att dots --------
__global__ __launch_bounds__(256) void gemm1_k(const float* __restrict__ x,
                                               const _Float16* __restrict__ W1f,
                                               const float* __restrict__ attl,
                                               const float* __restrict__ attr,
                                               __half* __restrict__ h1,
                                               float* __restrict__ ald,
                                               float* __restrict__ ard) {
    int t = threadIdx.x;
    int w = t >> 6, l = t & 63;
    int rw0 = blockIdx.x * 64 + w * 16;
    int arow = rw0 + (l & 15);
    if (arow >= N_NODES) arow = N_NODES - 1;  // clamp; OOB outputs are guarded
    int kg = l >> 4;                           // k-group 0..3
    const float4* x4 = (const float4*)(x + (size_t)arow * 512);
    const f16x8* w8 = (const f16x8*)W1f;

    f32x4 acc0 = {0.f, 0.f, 0.f, 0.f};
    f32x4 acc1 = {0.f, 0.f, 0.f, 0.f};
    f32x4 acc2 = {0.f, 0.f, 0.f, 0.f};
    f32x4 acc3 = {0.f, 0.f, 0.f, 0.f};

#pragma unroll 4
    for (int ks = 0; ks < 16; ++ks) {
        float4 a0 = x4[ks * 8 + kg * 2];
        float4 a1 = x4[ks * 8 + kg * 2 + 1];
        f16x8 af;
        af[0] = (_Float16)a0.x; af[1] = (_Float16)a0.y;
        af[2] = (_Float16)a0.z; af[3] = (_Float16)a0.w;
        af[4] = (_Float16)a1.x; af[5] = (_Float16)a1.y;
        af[6] = (_Float16)a1.z; af[7] = (_Float16)a1.w;
        f16x8 b0 = w8[(ks * 4 + 0) * 64 + l];
        f16x8 b1 = w8[(ks * 4 + 1) * 64 + l];
        f16x8 b2 = w8[(ks * 4 + 2) * 64 + l];
        f16x8 b3 = w8[(ks * 4 + 3) * 64 + l];
        acc0 = __builtin_amdgcn_mfma_f32_16x16x32_f16(af, b0, acc0, 0, 0, 0);
        acc1 = __builtin_amdgcn_mfma_f32_16x16x32_f16(af, b1, acc1, 0, 0, 0);
        acc2 = __builtin_amdgcn_mfma_f32_16x16x32_f16(af, b2, acc2, 0, 0, 0);
        acc3 = __builtin_amdgcn_mfma_f32_16x16x32_f16(af, b3, acc3, 0, 0, 0);
    }

    int col = l & 15;
    int hi = col >> 3;
    float al0 = attl[col], al1 = attl[16 + col], al2 = attl[32 + col], al3 = attl[48 + col];
    float ar0 = attr[col], ar1 = attr[16 + col], ar2 = attr[32 + col], ar3 = attr[48 + col];

#pragma unroll
    for (int reg = 0; reg < 4; ++reg) {
        int grow = rw0 + (l >> 4) * 4 + reg;
        bool v = grow < N_NODES;
        float c0 = acc0[reg], c1 = acc1[reg], c2 = acc2[reg], c3 = acc3[reg];
        if (v) {
            __half* hp = h1 + (size_t)grow * 64;
            hp[col]      = __float2half_rn(c0);
            hp[16 + col] = __float2half_rn(c1);
            hp[32 + col] = __float2half_rn(c2);
            hp[48 + col] = __float2half_rn(c3);
        }
        float vl0 = c0 * al0, vl1 = c1 * al1, vl2 = c2 * al2, vl3 = c3 * al3;
        float vr0 = c0 * ar0, vr1 = c1 * ar1, vr2 = c2 * ar2, vr3 = c3 * ar3;
        vl0 += __shfl_xor(vl0, 1); vl1 += __shfl_xor(vl1, 1);
        vl2 += __shfl_xor(vl2, 1); vl3 += __shfl_xor(vl3, 1);
        vr0 += __shfl_xor(vr0, 1); vr1 += __shfl_xor(vr1, 1);
        vr2 += __shfl_xor(vr2, 1); vr3 += __shfl_xor(vr3, 1);
        vl0 += __shfl_xor(vl0, 2); vl1 += __shfl_xor(vl1, 2);
        vl2 += __shfl_xor(vl2, 2); vl3 += __shfl_xor(vl3, 2);
        vr0 += __shfl_xor(vr0, 2); vr1 += __shfl_xor(vr1, 2);
        vr2 += __shfl_xor(vr2, 2); vr3 += __shfl_xor(vr3, 2);
        vl0 += __shfl_xor(vl0, 4); vl1 += __shfl_xor(vl1, 4);
        vl2 += __shfl_xor(vl2, 4); vl3 += __shfl_xor(vl3, 4);
        vr0 += __shfl_xor(vr0, 4); vr1 += __shfl_xor(vr1, 4);
        vr2 += __shfl_xor(vr2, 4); vr3 += __shfl_xor(vr3, 4);
        if (v && (l & 7) == 0) {
            float* alp = ald + (size_t)grow * 8;
            float* arp = ard + (size_t)grow * 8;
            alp[0 + hi] = vl0 * LOG2E; alp[2 + hi] = vl1 * LOG2E;
            alp[4 + hi] = vl2 * LOG2E; alp[6 + hi] = vl3 * LOG2E;
            arp[0 + hi] = vr0 * LOG2E; arp[2 + hi] = vr1 * LOG2E;
            arp[4 + hi] = vr2 * LOG2E; arp[6 + hi] = vr3 * LOG2E;
        }
    }
}

// ---------------- attn1 v3: lane = (node, head); 8 nodes per wave; 2-deep -----------
__global__ __launch_bounds__(256) void attn1_k(const __half* __restrict__ h1,
                                               const int* __restrict__ rowptr,
                                               const int* __restrict__ col,
                                               const float* __restrict__ ald,
                                               const float* __restrict__ ard,
                                               const float* __restrict__ b1,
                                               const int* __restrict__ perm,
                                               float* __restrict__ hout) {
    int gid = (blockIdx.x * 256 + threadIdx.x) >> 3;
    int h = threadIdx.x & 7;
    if (gid >= N_NODES) return;
    int node = perm[gid];
    const char* hb = (const char*)h1;
    unsigned hoff = (unsigned)h * 16u;

    f32x8 xi = unpack8(*(const float4*)(hb + (unsigned)node * 128u + hoff));
    float ardi = ard[node * 8 + h];
    int beg = rowptr[node], end = rowptr[node + 1];

    int s0 = col[beg], s1 = col[beg + 1];
    float4 rx0 = *(const float4*)(hb + (unsigned)s0 * 128u + hoff);
    float aj0 = ald[s0 * 8 + h];
    float4 rx1 = *(const float4*)(hb + (unsigned)s1 * 128u + hoff);
    float aj1 = ald[s1 * 8 + h];

    float m2 = -INFINITY, lsum = 0.f;
    f32x8 acc = {0.f, 0.f, 0.f, 0.f, 0.f, 0.f, 0.f, 0.f};
    for (int e = beg; e < end; e += 2) {
        int t0 = col[e + 2], t1 = col[e + 3];
        float4 ry0 = *(const float4*)(hb + (unsigned)t0 * 128u + hoff);
        float c0 = ald[t0 * 8 + h];
        float4 ry1 = *(const float4*)(hb + (unsigned)t1 * 128u + hoff);
        float c1 = ald[t1 * 8 + h];

        f32x8 xj0 = unpack8(rx0);
        f32x8 xj1 = unpack8(rx1);
        float d0 = 0.f, d1 = 0.f;
#pragma unroll
        for (int c = 0; c < 8; ++c) { d0 = fmaf(xi[c], xj0[c], d0); d1 = fmaf(xi[c], xj1[c], d1); }
        float g0 = (aj0 + ardi) * __builtin_amdgcn_rcpf(1.f + __builtin_amdgcn_exp2f(d0 * -LOG2E));
        float g1 = (aj1 + ardi) * __builtin_amdgcn_rcpf(1.f + __builtin_amdgcn_exp2f(d1 * -LOG2E));
        float a0 = fmaxf(g0, NEG_SLOPE * g0);
        float a1 = (e + 1 < end) ? fmaxf(g1, NEG_SLOPE * g1) : -INFINITY;
        float pm = fmaxf(a0, a1);
        if (__any(pm > m2 + 11.5f)) {
            float mn = fmaxf(m2, pm);
            float so = __builtin_amdgcn_exp2f(m2 - mn);
            lsum *= so;
#pragma unroll
            for (int c = 0; c < 8; ++c) acc[c] *= so;
            m2 = mn;
        }
        float p0 = __builtin_amdgcn_exp2f(a0 - m2);
        float p1 = __builtin_amdgcn_exp2f(a1 - m2);
        lsum += p0 + p1;
#pragma unroll
        for (int c = 0; c < 8; ++c) acc[c] += p0 * xj0[c] + p1 * xj1[c];
        rx0 = ry0; aj0 = c0; rx1 = ry1; aj1 = c1;
    }
    float rl = __builtin_amdgcn_rcpf(lsum);
    float4 bv0 = *(const float4*)(b1 + h * 8);
    float4 bv1 = *(const float4*)(b1 + h * 8 + 4);
    float ob[8];
    ob[0] = bv0.x; ob[1] = bv0.y; ob[2] = bv0.z; ob[3] = bv0.w;
    ob[4] = bv1.x; ob[5] = bv1.y; ob[6] = bv1.z; ob[7] = bv1.w;
    float4 o0, o1;
    float* op0 = (float*)&o0;
    float* op1 = (float*)&o1;
#pragma unroll
    for (int c = 0; c < 8; ++c) {
        float o = acc[c] * rl + ob[c];
        o = o > 0.f ? o : (__builtin_amdgcn_exp2f(o * LOG2E) - 1.f);  // ELU
        if (c < 4) op0[c] = o; else op1[c - 4] = o;
    }
    float4* dst = (float4*)(hout + (size_t)node * 64 + h * 8);
    dst[0] = o0;
    dst[1] = o1;
}

// ---------------- GEMM2: h2 = hout @ W2  (N x 64) @ (64 x 128), h2 stored fp16x2 ------
__global__ __launch_bounds__(256) void gemm2_k(const float* __restrict__ h,
                                               const float* __restrict__ W2,
                                               const float* __restrict__ attl,
                                               const float* __restrict__ attr,
                                               __half2* __restrict__ h2,
                                               float* __restrict__ ald,
                                               float* __restrict__ ard) {
    __shared__ float xs[32 * 64];
    int t = threadIdx.x;
    int row0 = blockIdx.x * 32;
    for (int i = t; i < 32 * 16; i += 256) {
        int r = i >> 4, q = i & 15;
        int gr = row0 + r;
        float4 v = make_float4(0.f, 0.f, 0.f, 0.f);
        if (gr < N_NODES) v = ((const float4*)h)[(size_t)gr * 16 + q];
        ((float4*)xs)[r * 16 + q] = v;
    }
    __syncthreads();
    int w = t >> 6, lane = t & 63;
    int r0 = w * 8;
    float2 acc[8];
#pragma unroll
    for (int r = 0; r < 8; ++r) acc[r] = make_float2(0.f, 0.f);
    for (int k = 0; k < 64; ++k) {
        float2 wv = ((const float2*)W2)[k * 64 + lane];
#pragma unroll
        for (int r = 0; r < 8; ++r) {
            float xv = xs[(r0 + r) * 64 + k];
            acc[r].x += xv * wv.x;
            acc[r].y += xv * wv.y;
        }
    }
    float2 al = ((const float2*)attl)[lane];
    float2 ar = ((const float2*)attr)[lane];
#pragma unroll
    for (int r = 0; r < 8; ++r) {
        int gr = row0 + r0 + r;
        float vl = acc[r].x * al.x + acc[r].y * al.y;
        float vr = acc[r].x * ar.x + acc[r].y * ar.y;
        vl += __shfl_xor(vl, 1); vr += __shfl_xor(vr, 1);
        vl += __shfl_xor(vl, 2); vr += __shfl_xor(vr, 2);
        vl += __shfl_xor(vl, 4); vr += __shfl_xor(vr, 4);
        if (gr < N_NODES) {
            h2[(size_t)gr * 64 + lane] = __floats2half2_rn(acc[r].x, acc[r].y);
            if ((lane & 7) == 0) {
                ald[gr * 8 + (lane >> 3)] = vl * LOG2E;
                ard[gr * 8 + (lane >> 3)] = vr * LOG2E;
            }
        }
    }
}

// ---------------- attn2 v3 (reverted to R13 2-deep): lane = (node, head) ------------
__global__ __launch_bounds__(256) void attn2_k(const __half* __restrict__ h2,
                                               const int* __restrict__ rowptr,
                                               const int* __restrict__ col,
                                               const float* __restrict__ ald,
                                               const float* __restrict__ ard,
                                               const float* __restrict__ b2,
                                               const int* __restrict__ perm,
                                               float* __restrict__ out) {
    int gid = (blockIdx.x * 256 + threadIdx.x) >> 3;
    int h = threadIdx.x & 7;
    if (gid >= N_NODES) return;
    int node = perm[gid];
    const char* hb = (const char*)h2;
    unsigned hoff = (unsigned)h * 32u;

    float4 ri0 = *(const float4*)(hb + (unsigned)node * 256u + hoff);
    float4 ri1 = *(const float4*)(hb + (unsigned)node * 256u + hoff + 16u);
    f32x8 xiA = unpack8(ri0);
    f32x8 xiB = unpack8(ri1);
    float ardi = ard[node * 8 + h];
    int beg = rowptr[node], end = rowptr[node + 1];

    int s0 = col[beg], s1 = col[beg + 1];
    float4 rx0a = *(const float4*)(hb + (unsigned)s0 * 256u + hoff);
    float4 rx0b = *(const float4*)(hb + (unsigned)s0 * 256u + hoff + 16u);
    float aj0 = ald[s0 * 8 + h];
    float4 rx1a = *(const float4*)(hb + (unsigned)s1 * 256u + hoff);
    float4 rx1b = *(const float4*)(hb + (unsigned)s1 * 256u + hoff + 16u);
    float aj1 = ald[s1 * 8 + h];

    float m2 = -INFINITY, lsum = 0.f;
    f32x16 acc;
#pragma unroll
    for (int c = 0; c < 16; ++c) acc[c] = 0.f;

    for (int e = beg; e < end; e += 2) {
        int t0 = col[e + 2], t1 = col[e + 3];
        float4 ry0a = *(const float4*)(hb + (unsigned)t0 * 256u + hoff);
        float4 ry0b = *(const float4*)(hb + (unsigned)t0 * 256u + hoff + 16u);
        float c0 = ald[t0 * 8 + h];
        float4 ry1a = *(const float4*)(hb + (unsigned)t1 * 256u + hoff);
        float4 ry1b = *(const float4*)(hb + (unsigned)t1 * 256u + hoff + 16u);
        float c1 = ald[t1 * 8 + h];

        f32x8 xj0a = unpack8(rx0a), xj0b = unpack8(rx0b);
        f32x8 xj1a = unpack8(rx1a), xj1b = unpack8(rx1b);
        float d0 = 0.f, d1 = 0.f;
#pragma unroll
        for (int c = 0; c < 8; ++c) {
            d0 = fmaf(xiA[c], xj0a[c], d0); d1 = fmaf(xiA[c], xj1a[c], d1);
            d0 = fmaf(xiB[c], xj0b[c], d0); d1 = fmaf(xiB[c], xj1b[c], d1);
        }
        float g0 = (aj0 + ardi) * __builtin_amdgcn_rcpf(1.f + __builtin_amdgcn_exp2f(d0 * -LOG2E));
        float g1 = (aj1 + ardi) * __builtin_amdgcn_rcpf(1.f + __builtin_amdgcn_exp2f(d1 * -LOG2E));
        float a0 = fmaxf(g0, NEG_SLOPE * g0);
        float a1 = (e + 1 < end) ? fmaxf(g1, NEG_SLOPE * g1) : -INFINITY;
        float pm = fmaxf(a0, a1);
        if (__any(pm > m2 + 11.5f)) {
            float mn = fmaxf(m2, pm);
            float so = __builtin_amdgcn_exp2f(m2 - mn);
            lsum *= so;
#pragma unroll
            for (int c = 0; c < 16; ++c) acc[c] *= so;
            m2 = mn;
        }
        float p0 = __builtin_amdgcn_exp2f(a0 - m2);
        float p1 = __builtin_amdgcn_exp2f(a1 - m2);
        lsum += p0 + p1;
#pragma unroll
        for (int c = 0; c < 8; ++c) {
            acc[c]     += p0 * xj0a[c] + p1 * xj1a[c];
            acc[c + 8] += p0 * xj0b[c] + p1 * xj1b[c];
        }
        rx0a = ry0a; rx0b = ry0b; aj0 = c0;
        rx1a = ry1a; rx1b = ry1b; aj1 = c1;
    }

    float rl = __builtin_amdgcn_rcpf(lsum);
    f32x16 v;
#pragma unroll
    for (int c = 0; c < 16; ++c) v[c] = acc[c] * rl;
#pragma unroll
    for (int c = 0; c < 16; ++c) {
        v[c] += __shfl_xor(v[c], 1);
        v[c] += __shfl_xor(v[c], 2);
        v[c] += __shfl_xor(v[c], 4);
    }
    float mx = -INFINITY;
#pragma unroll
    for (int c = 0; c < 16; ++c) { v[c] = v[c] * 0.125f + b2[c]; mx = fmaxf(mx, v[c]); }
    float se = 0.f;
#pragma unroll
    for (int c = 0; c < 16; ++c) se += __expf(v[c] - mx);
    float ls = __logf(se);
    if (h == 0) {
        float4 o;
        float* op = (float*)&o;
        float* dst = out + (size_t)node * 16;
#pragma unroll
        for (int q = 0; q < 4; ++q) {
#pragma unroll
            for (int c = 0; c < 4; ++c) op[c] = v[q * 4 + c] - mx - ls;
            ((float4*)dst)[q] = o;
        }
    }
}

// ---------------- host ----------------
extern "C" void kernel_launch(void* const* d_in, const int* in_sizes, int n_in,
                              void* d_out, int out_size, void* d_ws, size_t ws_size,
                              hipStream_t stream) {
    const float* x     = (const float*)d_in[0];
    const int*   ei    = (const int*)d_in[1];
    const float* W1    = (const float*)d_in[2];
    const float* attl1 = (const float*)d_in[3];
    const float* attr1 = (const float*)d_in[4];
    const float* b1    = (const float*)d_in[5];
    const float* W2    = (const float*)d_in[6];
    const float* attl2 = (const float*)d_in[7];
    const float* attr2 = (const float*)d_in[8];
    const float* b2    = (const float*)d_in[9];
    float* out = (float*)d_out;

    char* ws = (char*)d_ws;
    size_t off = 0;
    auto alloc = [&](size_t bytes) {
        size_t o = off;
        off += (bytes + 255) & ~(size_t)255;
        return o;
    };
    size_t o_flag   = alloc(4);
    size_t o_counts = alloc((size_t)N_NODES * 4);
    size_t o_rank   = alloc((size_t)N_EDGES * 4);
    size_t o_rowptr = alloc((size_t)(N_NODES + 1) * 4);
    size_t o_bsums  = alloc(1024 * 4);
    size_t o_col    = alloc((size_t)(EPRIME + 8) * 4);   // +8 sentinel pad
    size_t o_h1     = alloc((size_t)N_NODES * 64 * 4);   // (over-alloc; h1 is fp16)
    size_t o_hout   = alloc((size_t)N_NODES * 64 * 4);
    size_t o_h2     = alloc((size_t)N_NODES * 128 * 4);  // (over-alloc; h2 is fp16)
    size_t o_w1f    = alloc((size_t)512 * 64 * 2);       // fp16 swizzled W1
    size_t o_perm   = alloc((size_t)N_NODES * 4);
    size_t o_dbins  = alloc(256 * 4);
    size_t o_dstart = alloc(256 * 4);
    size_t o_dfill  = alloc(256 * 4);

    size_t aldsz = ((size_t)N_NODES * 8 * 4 + 255) & ~(size_t)255;
    size_t o_ald1 = o_h2;
    size_t o_ard1 = o_h2 + aldsz;
    size_t o_ald2 = o_h1;
    size_t o_ard2 = o_h1 + aldsz;

    unsigned* flag = (unsigned*)(ws + o_flag);
    int* counts = (int*)(ws + o_counts);
    int* rank   = (int*)(ws + o_rank);
    int* rowptr = (int*)(ws + o_rowptr);
    int* bsums  = (int*)(ws + o_bsums);
    int* col    = (int*)(ws + o_col);
    __half* h1  = (__half*)(ws + o_h1);
    float* hout = (float*)(ws + o_hout);
    __half* h2  = (__half*)(ws + o_h2);
    _Float16* w1f = (_Float16*)(ws + o_w1f);
    int* perm   = (int*)(ws + o_perm);
    int* dbins  = (int*)(ws + o_dbins);
    int* dstart = (int*)(ws + o_dstart);
    int* dfill  = (int*)(ws + o_dfill);
    float* ald1 = (float*)(ws + o_ald1);
    float* ard1 = (float*)(ws + o_ard1);
    float* ald2 = (float*)(ws + o_ald2);
    float* ard2 = (float*)(ws + o_ard2);

    int nscan = (N_NODES + 1 + 1023) / 1024;  // 99
    int nblk  = (N_NODES + 255) / 256;
    int nscat = 8 * ((N_EDGES + SCHUNK - 1) / SCHUNK);

    hipLaunchKernelGGL(detect_k, dim3(1), dim3(256), 0, stream, (const unsigned*)ei, flag);
    hipLaunchKernelGGL(init_k, dim3(nblk), dim3(256), 0, stream, counts, dbins);
    hipLaunchKernelGGL(countrank_k, dim3((N_EDGES + 255) / 256), dim3(256), 0, stream,
                       ei, flag, counts, rank);
    // degree-sorted permutation (two-level counting sort over 256 degree bins)
    hipLaunchKernelGGL(hist_k, dim3(nblk), dim3(256), 0, stream, counts, dbins);
    hipLaunchKernelGGL(hscan_k, dim3(1), dim3(256), 0, stream, dbins, dstart, dfill);
    hipLaunchKernelGGL(hscatter_k, dim3(nblk), dim3(256), 0, stream, counts, dstart, dfill, perm);
    hipLaunchKernelGGL(scan1_k, dim3(nscan), dim3(256), 0, stream, counts, rowptr, bsums);
    hipLaunchKernelGGL(scan3_k, dim3(nscan), dim3(256), 0, stream, rowptr, bsums, col);
    hipLaunchKernelGGL(scatter2_k, dim3(nscat), dim3(256), 0, stream,
                       ei, flag, rowptr, rank, col);
    hipLaunchKernelGGL(w1cvt_k, dim3(128), dim3(256), 0, stream, W1, w1f);
    hipLaunchKernelGGL(gemm1_k, dim3((N_NODES + 63) / 64), dim3(256), 0, stream,
                       x, w1f, attl1, attr1, h1, ald1, ard1);
    hipLaunchKernelGGL(attn1_k, dim3((N_NODES * 8 + 255) / 256), dim3(256), 0, stream,
                       h1, rowptr, col, ald1, ard1, b1, perm, hout);
    hipLaunchKernelGGL(gemm2_k, dim3((N_NODES + 31) / 32), dim3(256), 0, stream,
                       hout, W2, attl2, attr2, (__half2*)h2, ald2, ard2);
    hipLaunchKernelGGL(attn2_k, dim3((N_NODES * 8 + 255) / 256), dim3(256), 0, stream,
                       h2, rowptr, col, ald2, ard2, b2, perm, out);
}

// Round 17
// 381.284 us; speedup vs baseline: 1.1019x; 1.0350x over previous
//
#include <hip/hip_runtime.h>
#include <hip/hip_fp16.h>
#include <math.h>

#define N_NODES 100000
#define N_EDGES 1600000
#define EPRIME  (N_EDGES + N_NODES)
#define NEG_SLOPE 0.2f
#define LOG2E 1.44269504f
#define NBLK 391           // ceil(N_NODES/256)
#define NSCAN 99           // ceil((N_NODES+1)/1024)
#define SCHUNK 2048
#define NSCAT (8 * ((N_EDGES + SCHUNK - 1) / SCHUNK))

typedef _Float16 f16x8 __attribute__((ext_vector_type(8)));
typedef float f32x4 __attribute__((ext_vector_type(4)));
typedef float f32x8 __attribute__((ext_vector_type(8)));
typedef float f32x16 __attribute__((ext_vector_type(16)));

__device__ __forceinline__ f32x8 unpack8(float4 r) {
    f32x8 o;
    float2 f;
    f = __half22float2(__builtin_bit_cast(__half2, r.x)); o[0] = f.x; o[1] = f.y;
    f = __half22float2(__builtin_bit_cast(__half2, r.y)); o[2] = f.x; o[3] = f.y;
    f = __half22float2(__builtin_bit_cast(__half2, r.z)); o[4] = f.x; o[5] = f.y;
    f = __half22float2(__builtin_bit_cast(__half2, r.w)); o[6] = f.x; o[7] = f.y;
    return o;
}

// ---------------- prep: detect dtype + counts init + dbins zero + W1 cvt ------------
// All input-only / mutually independent -> one branched grid (saves 3 launches).
__global__ __launch_bounds__(256) void prep_k(const unsigned* __restrict__ eiw,
                                              unsigned* __restrict__ flag,
                                              int* __restrict__ counts,
                                              int* __restrict__ dbins,
                                              const float* __restrict__ W1,
                                              _Float16* __restrict__ W1f) {
    int bid = blockIdx.x;
    int n = bid * 256 + threadIdx.x;
    if (n < N_NODES) counts[n] = 1;  // slot 0 of each row = self loop
    if (bid == 0) dbins[threadIdx.x] = 0;
    if (bid == 1) {
        __shared__ int any;
        if (threadIdx.x == 0) any = 0;
        __syncthreads();
        int nz = 0;
        for (int i = threadIdx.x; i < 1024; i += 256)
            if (eiw[2 * i + 1] != 0u) nz = 1;
        if (nz) atomicOr(&any, 1);
        __syncthreads();
        if (threadIdx.x == 0) flag[0] = any ? 0u : 1u;  // 1 => int64
    }
    if (bid >= 2 && bid < 130) {
        int idx = (bid - 2) * 256 + threadIdx.x;  // 0..32767
        int j    = idx & 7;
        int lane = (idx >> 3) & 63;
        int nt   = (idx >> 9) & 3;
        int ks   = idx >> 11;
        int k = ks * 32 + (lane >> 4) * 8 + j;
        int c = nt * 16 + (lane & 15);
        W1f[idx] = (_Float16)W1[k * 64 + c];
    }
}

__global__ __launch_bounds__(256) void countrank_k(const int* __restrict__ ei,
                                                   const unsigned* __restrict__ flag,
                                                   int* __restrict__ counts,
                                                   int* __restrict__ rank) {
    int e = blockIdx.x * blockDim.x + threadIdx.x;
    if (e >= N_EDGES) return;
    int d = flag[0] ? ei[2 * (N_EDGES + e)] : ei[N_EDGES + e];
    rank[e] = atomicAdd(&counts[d], 1);
}

// ---------------- hist + scan1 fused (both read final counts, disjoint outputs) -----
__global__ __launch_bounds__(256) void histscan1_k(const int* __restrict__ counts,
                                                   int* __restrict__ dbins,
                                                   int* __restrict__ rowptr,
                                                   int* __restrict__ bsums) {
    __shared__ int s[256];
    int t = threadIdx.x;
    int bid = blockIdx.x;
    if (bid < NBLK) {
        // hist: per-block LDS histogram, then bulk global atomics
        s[t] = 0;
        __syncthreads();
        int n = bid * 256 + t;
        if (n < N_NODES) atomicAdd(&s[min(counts[n], 255)], 1);
        __syncthreads();
        int c = s[t];
        if (c) atomicAdd(&dbins[t], c);
    } else {
        // scan1: block-local exclusive scan of counts -> rowptr, block sums
        int sb = bid - NBLK;
        int base = sb * 1024 + t * 4;
        int v[4];
#pragma unroll
        for (int j = 0; j < 4; ++j)
            v[j] = (base + j < N_NODES) ? counts[base + j] : 0;
        int tsum = v[0] + v[1] + v[2] + v[3];
        s[t] = tsum;
        __syncthreads();
        for (int off = 1; off < 256; off <<= 1) {
            int x = (t >= off) ? s[t - off] : 0;
            __syncthreads();
            s[t] += x;
            __syncthreads();
        }
        if (t == 255) bsums[sb] = s[255];
        int run = s[t] - tsum;
#pragma unroll
        for (int j = 0; j < 4; ++j) {
            if (base + j <= N_NODES) rowptr[base + j] = run;
            run += v[j];
        }
    }
}

// ---------------- hscan + scan3 fused (single-dep each, disjoint outputs) -----------
// block 0: bin prefix scan; blocks 1..NSCAN: rowptr finalize + self-loop cols + pad
__global__ __launch_bounds__(256) void hscan_scan3_k(const int* __restrict__ dbins,
                                                     int* __restrict__ dstart,
                                                     int* __restrict__ dfill,
                                                     int* __restrict__ rowptr,
                                                     const int* __restrict__ bsums,
                                                     int* __restrict__ col) {
    __shared__ int s[256];
    int t = threadIdx.x;
    if (blockIdx.x == 0) {
        int v = dbins[t];
        s[t] = v;
        __syncthreads();
        for (int off = 1; off < 256; off <<= 1) {
            int x = (t >= off) ? s[t - off] : 0;
            __syncthreads();
            s[t] += x;
            __syncthreads();
        }
        dstart[t] = s[t] - v;  // exclusive
        dfill[t] = 0;
    } else {
        int bid = blockIdx.x - 1;  // 0..NSCAN-1
        s[t] = (t < bid) ? bsums[t] : 0;  // NSCAN <= 256
        __syncthreads();
        for (int off = 128; off > 0; off >>= 1) {
            if (t < off) s[t] += s[t + off];
            __syncthreads();
        }
        int add = s[0];
        int base = bid * 1024 + t * 4;
#pragma unroll
        for (int j = 0; j < 4; ++j) {
            int idx = base + j;
            if (idx <= N_NODES) {
                int rv = rowptr[idx] + add;
                rowptr[idx] = rv;
                if (idx < N_NODES) col[rv] = idx;  // self loop at slot 0
            }
        }
        if (bid == 0 && t < 8) col[EPRIME + t] = 0;  // sentinel pad
    }
}

// ---------------- hscatter + scatter2 fused ------------------------------------------
// blocks [0,NBLK): perm scatter (two-level sort); blocks [NBLK, NBLK+NSCAT):
// XCD-partitioned atomic-free col scatter (R13: write amplification 16x -> 1x).
__global__ __launch_bounds__(256) void hscat_scat2_k(const int* __restrict__ counts,
                                                     const int* __restrict__ dstart,
                                                     int* __restrict__ dfill,
                                                     int* __restrict__ perm,
                                                     const int* __restrict__ ei,
                                                     const unsigned* __restrict__ flag,
                                                     const int* __restrict__ rowptr,
                                                     const int* __restrict__ rank,
                                                     int* __restrict__ col) {
    if (blockIdx.x < NBLK) {
        __shared__ int lh[256];
        __shared__ int lbase[256];
        lh[threadIdx.x] = 0;
        __syncthreads();
        int n = blockIdx.x * 256 + threadIdx.x;
        int b = 0, lrank = 0;
        bool valid = n < N_NODES;
        if (valid) {
            b = min(counts[n], 255);
            lrank = atomicAdd(&lh[b], 1);
        }
        __syncthreads();
        int c = lh[threadIdx.x];
        lbase[threadIdx.x] = c ? atomicAdd(&dfill[threadIdx.x], c) : 0;
        __syncthreads();
        if (valid) perm[dstart[b] + lbase[b] + lrank] = n;
    } else {
        int sb = blockIdx.x - NBLK;
        int xcd = sb & 7;
        int base = (sb >> 3) * SCHUNK;
        int lo = xcd * 12500, hi = lo + 12500;
        int lim = min(base + SCHUNK, N_EDGES);
        bool f = flag[0] != 0;
        for (int i = base + threadIdx.x; i < lim; i += 256) {
            int d = f ? ei[2 * (N_EDGES + i)] : ei[N_EDGES + i];
            if (d >= lo && d < hi) {
                int s = f ? ei[2 * i] : ei[i];
                col[rowptr[d] + rank[i]] = s;
            }
        }
    }
}

// ---------------- GEMM1 (MFMA): h1 = x @ W1, h1 fp16 + fused att dots --------
__global__ __launch_bounds__(256) void gemm1_k(const float* __restrict__ x,
                                               const _Float16* __restrict__ W1f,
                                               const float* __restrict__ attl,
                                               const float* __restrict__ attr,
                                               __half* __restrict__ h1,
                                               float* __restrict__ ald,
                                               float* __restrict__ ard) {
    int t = threadIdx.x;
    int w = t >> 6, l = t & 63;
    int rw0 = blockIdx.x * 64 + w * 16;
    int arow = rw0 + (l & 15);
    if (arow >= N_NODES) arow = N_NODES - 1;  // clamp; OOB outputs are guarded
    int kg = l >> 4;                           // k-group 0..3
    const float4* x4 = (const float4*)(x + (size_t)arow * 512);
    const f16x8* w8 = (const f16x8*)W1f;

    f32x4 acc0 = {0.f, 0.f, 0.f, 0.f};
    f32x4 acc1 = {0.f, 0.f, 0.f, 0.f};
    f32x4 acc2 = {0.f, 0.f, 0.f, 0.f};
    f32x4 acc3 = {0.f, 0.f, 0.f, 0.f};

#pragma unroll 4
    for (int ks = 0; ks < 16; ++ks) {
        float4 a0 = x4[ks * 8 + kg * 2];
        float4 a1 = x4[ks * 8 + kg * 2 + 1];
        f16x8 af;
        af[0] = (_Float16)a0.x; af[1] = (_Float16)a0.y;
        af[2] = (_Float16)a0.z; af[3] = (_Float16)a0.w;
        af[4] = (_Float16)a1.x; af[5] = (_Float16)a1.y;
        af[6] = (_Float16)a1.z; af[7] = (_Float16)a1.w;
        f16x8 b0 = w8[(ks * 4 + 0) * 64 + l];
        f16x8 b1 = w8[(ks * 4 + 1) * 64 + l];
        f16x8 b2 = w8[(ks * 4 + 2) * 64 + l];
        f16x8 b3 = w8[(ks * 4 + 3) * 64 + l];
        acc0 = __builtin_amdgcn_mfma_f32_16x16x32_f16(af, b0, acc0, 0, 0, 0);
        acc1 = __builtin_amdgcn_mfma_f32_16x16x32_f16(af, b1, acc1, 0, 0, 0);
        acc2 = __builtin_amdgcn_mfma_f32_16x16x32_f16(af, b2, acc2, 0, 0, 0);
        acc3 = __builtin_amdgcn_mfma_f32_16x16x32_f16(af, b3, acc3, 0, 0, 0);
    }

    int col = l & 15;
    int hi = col >> 3;
    float al0 = attl[col], al1 = attl[16 + col], al2 = attl[32 + col], al3 = attl[48 + col];
    float ar0 = attr[col], ar1 = attr[16 + col], ar2 = attr[32 + col], ar3 = attr[48 + col];

#pragma unroll
    for (int reg = 0; reg < 4; ++reg) {
        int grow = rw0 + (l >> 4) * 4 + reg;
        bool v = grow < N_NODES;
        float c0 = acc0[reg], c1 = acc1[reg], c2 = acc2[reg], c3 = acc3[reg];
        if (v) {
            __half* hp = h1 + (size_t)grow * 64;
            hp[col]      = __float2half_rn(c0);
            hp[16 + col] = __float2half_rn(c1);
            hp[32 + col] = __float2half_rn(c2);
            hp[48 + col] = __float2half_rn(c3);
        }
        float vl0 = c0 * al0, vl1 = c1 * al1, vl2 = c2 * al2, vl3 = c3 * al3;
        float vr0 = c0 * ar0, vr1 = c1 * ar1, vr2 = c2 * ar2, vr3 = c3 * ar3;
        vl0 += __shfl_xor(vl0, 1); vl1 += __shfl_xor(vl1, 1);
        vl2 += __shfl_xor(vl2, 1); vl3 += __shfl_xor(vl3, 1);
        vr0 += __shfl_xor(vr0, 1); vr1 += __shfl_xor(vr1, 1);
        vr2 += __shfl_xor(vr2, 1); vr3 += __shfl_xor(vr3, 1);
        vl0 += __shfl_xor(vl0, 2); vl1 += __shfl_xor(vl1, 2);
        vl2 += __shfl_xor(vl2, 2); vl3 += __shfl_xor(vl3, 2);
        vr0 += __shfl_xor(vr0, 2); vr1 += __shfl_xor(vr1, 2);
        vr2 += __shfl_xor(vr2, 2); vr3 += __shfl_xor(vr3, 2);
        vl0 += __shfl_xor(vl0, 4); vl1 += __shfl_xor(vl1, 4);
        vl2 += __shfl_xor(vl2, 4); vl3 += __shfl_xor(vl3, 4);
        vr0 += __shfl_xor(vr0, 4); vr1 += __shfl_xor(vr1, 4);
        vr2 += __shfl_xor(vr2, 4); vr3 += __shfl_xor(vr3, 4);
        if (v && (l & 7) == 0) {
            float* alp = ald + (size_t)grow * 8;
            float* arp = ard + (size_t)grow * 8;
            alp[0 + hi] = vl0 * LOG2E; alp[2 + hi] = vl1 * LOG2E;
            alp[4 + hi] = vl2 * LOG2E; alp[6 + hi] = vl3 * LOG2E;
            arp[0 + hi] = vr0 * LOG2E; arp[2 + hi] = vr1 * LOG2E;
            arp[4 + hi] = vr2 * LOG2E; arp[6 + hi] = vr3 * LOG2E;
        }
    }
}

// ---------------- attn1 v3: lane = (node, head); 8 nodes per wave; 2-deep -----------
__global__ __launch_bounds__(256) void attn1_k(const __half* __restrict__ h1,
                                               const int* __restrict__ rowptr,
                                               const int* __restrict__ col,
                                               const float* __restrict__ ald,
                                               const float* __restrict__ ard,
                                               const float* __restrict__ b1,
                                               const int* __restrict__ perm,
                                               float* __restrict__ hout) {
    int gid = (blockIdx.x * 256 + threadIdx.x) >> 3;
    int h = threadIdx.x & 7;
    if (gid >= N_NODES) return;
    int node = perm[gid];
    const char* hb = (const char*)h1;
    unsigned hoff = (unsigned)h * 16u;

    f32x8 xi = unpack8(*(const float4*)(hb + (unsigned)node * 128u + hoff));
    float ardi = ard[node * 8 + h];
    int beg = rowptr[node], end = rowptr[node + 1];

    int s0 = col[beg], s1 = col[beg + 1];
    float4 rx0 = *(const float4*)(hb + (unsigned)s0 * 128u + hoff);
    float aj0 = ald[s0 * 8 + h];
    float4 rx1 = *(const float4*)(hb + (unsigned)s1 * 128u + hoff);
    float aj1 = ald[s1 * 8 + h];

    float m2 = -INFINITY, lsum = 0.f;
    f32x8 acc = {0.f, 0.f, 0.f, 0.f, 0.f, 0.f, 0.f, 0.f};
    for (int e = beg; e < end; e += 2) {
        int t0 = col[e + 2], t1 = col[e + 3];
        float4 ry0 = *(const float4*)(hb + (unsigned)t0 * 128u + hoff);
        float c0 = ald[t0 * 8 + h];
        float4 ry1 = *(const float4*)(hb + (unsigned)t1 * 128u + hoff);
        float c1 = ald[t1 * 8 + h];

        f32x8 xj0 = unpack8(rx0);
        f32x8 xj1 = unpack8(rx1);
        float d0 = 0.f, d1 = 0.f;
#pragma unroll
        for (int c = 0; c < 8; ++c) { d0 = fmaf(xi[c], xj0[c], d0); d1 = fmaf(xi[c], xj1[c], d1); }
        float g0 = (aj0 + ardi) * __builtin_amdgcn_rcpf(1.f + __builtin_amdgcn_exp2f(d0 * -LOG2E));
        float g1 = (aj1 + ardi) * __builtin_amdgcn_rcpf(1.f + __builtin_amdgcn_exp2f(d1 * -LOG2E));
        float a0 = fmaxf(g0, NEG_SLOPE * g0);
        float a1 = (e + 1 < end) ? fmaxf(g1, NEG_SLOPE * g1) : -INFINITY;
        float pm = fmaxf(a0, a1);
        if (__any(pm > m2 + 11.5f)) {
            float mn = fmaxf(m2, pm);
            float so = __builtin_amdgcn_exp2f(m2 - mn);
            lsum *= so;
#pragma unroll
            for (int c = 0; c < 8; ++c) acc[c] *= so;
            m2 = mn;
        }
        float p0 = __builtin_amdgcn_exp2f(a0 - m2);
        float p1 = __builtin_amdgcn_exp2f(a1 - m2);
        lsum += p0 + p1;
#pragma unroll
        for (int c = 0; c < 8; ++c) acc[c] += p0 * xj0[c] + p1 * xj1[c];
        rx0 = ry0; aj0 = c0; rx1 = ry1; aj1 = c1;
    }
    float rl = __builtin_amdgcn_rcpf(lsum);
    float4 bv0 = *(const float4*)(b1 + h * 8);
    float4 bv1 = *(const float4*)(b1 + h * 8 + 4);
    float ob[8];
    ob[0] = bv0.x; ob[1] = bv0.y; ob[2] = bv0.z; ob[3] = bv0.w;
    ob[4] = bv1.x; ob[5] = bv1.y; ob[6] = bv1.z; ob[7] = bv1.w;
    float4 o0, o1;
    float* op0 = (float*)&o0;
    float* op1 = (float*)&o1;
#pragma unroll
    for (int c = 0; c < 8; ++c) {
        float o = acc[c] * rl + ob[c];
        o = o > 0.f ? o : (__builtin_amdgcn_exp2f(o * LOG2E) - 1.f);  // ELU
        if (c < 4) op0[c] = o; else op1[c - 4] = o;
    }
    float4* dst = (float4*)(hout + (size_t)node * 64 + h * 8);
    dst[0] = o0;
    dst[1] = o1;
}

// ---------------- GEMM2: h2 = hout @ W2  (N x 64) @ (64 x 128), h2 stored fp16x2 ------
__global__ __launch_bounds__(256) void gemm2_k(const float* __restrict__ h,
                                               const float* __restrict__ W2,
                                               const float* __restrict__ attl,
                                               const float* __restrict__ attr,
                                               __half2* __restrict__ h2,
                                               float* __restrict__ ald,
                                               float* __restrict__ ard) {
    __shared__ float xs[32 * 64];
    int t = threadIdx.x;
    int row0 = blockIdx.x * 32;
    for (int i = t; i < 32 * 16; i += 256) {
        int r = i >> 4, q = i & 15;
        int gr = row0 + r;
        float4 v = make_float4(0.f, 0.f, 0.f, 0.f);
        if (gr < N_NODES) v = ((const float4*)h)[(size_t)gr * 16 + q];
        ((float4*)xs)[r * 16 + q] = v;
    }
    __syncthreads();
    int w = t >> 6, lane = t & 63;
    int r0 = w * 8;
    float2 acc[8];
#pragma unroll
    for (int r = 0; r < 8; ++r) acc[r] = make_float2(0.f, 0.f);
    for (int k = 0; k < 64; ++k) {
        float2 wv = ((const float2*)W2)[k * 64 + lane];
#pragma unroll
        for (int r = 0; r < 8; ++r) {
            float xv = xs[(r0 + r) * 64 + k];
            acc[r].x += xv * wv.x;
            acc[r].y += xv * wv.y;
        }
    }
    float2 al = ((const float2*)attl)[lane];
    float2 ar = ((const float2*)attr)[lane];
#pragma unroll
    for (int r = 0; r < 8; ++r) {
        int gr = row0 + r0 + r;
        float vl = acc[r].x * al.x + acc[r].y * al.y;
        float vr = acc[r].x * ar.x + acc[r].y * ar.y;
        vl += __shfl_xor(vl, 1); vr += __shfl_xor(vr, 1);
        vl += __shfl_xor(vl, 2); vr += __shfl_xor(vr, 2);
        vl += __shfl_xor(vl, 4); vr += __shfl_xor(vr, 4);
        if (gr < N_NODES) {
            h2[(size_t)gr * 64 + lane] = __floats2half2_rn(acc[r].x, acc[r].y);
            if ((lane & 7) == 0) {
                ald[gr * 8 + (lane >> 3)] = vl * LOG2E;
                ard[gr * 8 + (lane >> 3)] = vr * LOG2E;
            }
        }
    }
}

// ---------------- attn2 v3: lane = (node, head); 16 ch/lane; 2-deep ------------------
__global__ __launch_bounds__(256) void attn2_k(const __half* __restrict__ h2,
                                               const int* __restrict__ rowptr,
                                               const int* __restrict__ col,
                                               const float* __restrict__ ald,
                                               const float* __restrict__ ard,
                                               const float* __restrict__ b2,
                                               const int* __restrict__ perm,
                                               float* __restrict__ out) {
    int gid = (blockIdx.x * 256 + threadIdx.x) >> 3;
    int h = threadIdx.x & 7;
    if (gid >= N_NODES) return;
    int node = perm[gid];
    const char* hb = (const char*)h2;
    unsigned hoff = (unsigned)h * 32u;

    float4 ri0 = *(const float4*)(hb + (unsigned)node * 256u + hoff);
    float4 ri1 = *(const float4*)(hb + (unsigned)node * 256u + hoff + 16u);
    f32x8 xiA = unpack8(ri0);
    f32x8 xiB = unpack8(ri1);
    float ardi = ard[node * 8 + h];
    int beg = rowptr[node], end = rowptr[node + 1];

    int s0 = col[beg], s1 = col[beg + 1];
    float4 rx0a = *(const float4*)(hb + (unsigned)s0 * 256u + hoff);
    float4 rx0b = *(const float4*)(hb + (unsigned)s0 * 256u + hoff + 16u);
    float aj0 = ald[s0 * 8 + h];
    float4 rx1a = *(const float4*)(hb + (unsigned)s1 * 256u + hoff);
    float4 rx1b = *(const float4*)(hb + (unsigned)s1 * 256u + hoff + 16u);
    float aj1 = ald[s1 * 8 + h];

    float m2 = -INFINITY, lsum = 0.f;
    f32x16 acc;
#pragma unroll
    for (int c = 0; c < 16; ++c) acc[c] = 0.f;

    for (int e = beg; e < end; e += 2) {
        int t0 = col[e + 2], t1 = col[e + 3];
        float4 ry0a = *(const float4*)(hb + (unsigned)t0 * 256u + hoff);
        float4 ry0b = *(const float4*)(hb + (unsigned)t0 * 256u + hoff + 16u);
        float c0 = ald[t0 * 8 + h];
        float4 ry1a = *(const float4*)(hb + (unsigned)t1 * 256u + hoff);
        float4 ry1b = *(const float4*)(hb + (unsigned)t1 * 256u + hoff + 16u);
        float c1 = ald[t1 * 8 + h];

        f32x8 xj0a = unpack8(rx0a), xj0b = unpack8(rx0b);
        f32x8 xj1a = unpack8(rx1a), xj1b = unpack8(rx1b);
        float d0 = 0.f, d1 = 0.f;
#pragma unroll
        for (int c = 0; c < 8; ++c) {
            d0 = fmaf(xiA[c], xj0a[c], d0); d1 = fmaf(xiA[c], xj1a[c], d1);
            d0 = fmaf(xiB[c], xj0b[c], d0); d1 = fmaf(xiB[c], xj1b[c], d1);
        }
        float g0 = (aj0 + ardi) * __builtin_amdgcn_rcpf(1.f + __builtin_amdgcn_exp2f(d0 * -LOG2E));
        float g1 = (aj1 + ardi) * __builtin_amdgcn_rcpf(1.f + __builtin_amdgcn_exp2f(d1 * -LOG2E));
        float a0 = fmaxf(g0, NEG_SLOPE * g0);
        float a1 = (e + 1 < end) ? fmaxf(g1, NEG_SLOPE * g1) : -INFINITY;
        float pm = fmaxf(a0, a1);
        if (__any(pm > m2 + 11.5f)) {
            float mn = fmaxf(m2, pm);
            float so = __builtin_amdgcn_exp2f(m2 - mn);
            lsum *= so;
#pragma unroll
            for (int c = 0; c < 16; ++c) acc[c] *= so;
            m2 = mn;
        }
        float p0 = __builtin_amdgcn_exp2f(a0 - m2);
        float p1 = __builtin_amdgcn_exp2f(a1 - m2);
        lsum += p0 + p1;
#pragma unroll
        for (int c = 0; c < 8; ++c) {
            acc[c]     += p0 * xj0a[c] + p1 * xj1a[c];
            acc[c + 8] += p0 * xj0b[c] + p1 * xj1b[c];
        }
        rx0a = ry0a; rx0b = ry0b; aj0 = c0;
        rx1a = ry1a; rx1b = ry1b; aj1 = c1;
    }

    float rl = __builtin_amdgcn_rcpf(lsum);
    f32x16 v;
#pragma unroll
    for (int c = 0; c < 16; ++c) v[c] = acc[c] * rl;
#pragma unroll
    for (int c = 0; c < 16; ++c) {
        v[c] += __shfl_xor(v[c], 1);
        v[c] += __shfl_xor(v[c], 2);
        v[c] += __shfl_xor(v[c], 4);
    }
    float mx = -INFINITY;
#pragma unroll
    for (int c = 0; c < 16; ++c) { v[c] = v[c] * 0.125f + b2[c]; mx = fmaxf(mx, v[c]); }
    float se = 0.f;
#pragma unroll
    for (int c = 0; c < 16; ++c) se += __expf(v[c] - mx);
    float ls = __logf(se);
    if (h == 0) {
        float4 o;
        float* op = (float*)&o;
        float* dst = out + (size_t)node * 16;
#pragma unroll
        for (int q = 0; q < 4; ++q) {
#pragma unroll
            for (int c = 0; c < 4; ++c) op[c] = v[q * 4 + c] - mx - ls;
            ((float4*)dst)[q] = o;
        }
    }
}

// ---------------- host ----------------
extern "C" void kernel_launch(void* const* d_in, const int* in_sizes, int n_in,
                              void* d_out, int out_size, void* d_ws, size_t ws_size,
                              hipStream_t stream) {
    const float* x     = (const float*)d_in[0];
    const int*   ei    = (const int*)d_in[1];
    const float* W1    = (const float*)d_in[2];
    const float* attl1 = (const float*)d_in[3];
    const float* attr1 = (const float*)d_in[4];
    const float* b1    = (const float*)d_in[5];
    const float* W2    = (const float*)d_in[6];
    const float* attl2 = (const float*)d_in[7];
    const float* attr2 = (const float*)d_in[8];
    const float* b2    = (const float*)d_in[9];
    float* out = (float*)d_out;

    char* ws = (char*)d_ws;
    size_t off = 0;
    auto alloc = [&](size_t bytes) {
        size_t o = off;
        off += (bytes + 255) & ~(size_t)255;
        return o;
    };
    size_t o_flag   = alloc(4);
    size_t o_counts = alloc((size_t)N_NODES * 4);
    size_t o_rank   = alloc((size_t)N_EDGES * 4);
    size_t o_rowptr = alloc((size_t)(N_NODES + 1) * 4);
    size_t o_bsums  = alloc(1024 * 4);
    size_t o_col    = alloc((size_t)(EPRIME + 8) * 4);   // +8 sentinel pad
    size_t o_h1     = alloc((size_t)N_NODES * 64 * 4);   // (over-alloc; h1 is fp16)
    size_t o_hout   = alloc((size_t)N_NODES * 64 * 4);
    size_t o_h2     = alloc((size_t)N_NODES * 128 * 4);  // (over-alloc; h2 is fp16)
    size_t o_w1f    = alloc((size_t)512 * 64 * 2);       // fp16 swizzled W1
    size_t o_perm   = alloc((size_t)N_NODES * 4);
    size_t o_dbins  = alloc(256 * 4);
    size_t o_dstart = alloc(256 * 4);
    size_t o_dfill  = alloc(256 * 4);

    size_t aldsz = ((size_t)N_NODES * 8 * 4 + 255) & ~(size_t)255;
    size_t o_ald1 = o_h2;
    size_t o_ard1 = o_h2 + aldsz;
    size_t o_ald2 = o_h1;
    size_t o_ard2 = o_h1 + aldsz;

    unsigned* flag = (unsigned*)(ws + o_flag);
    int* counts = (int*)(ws + o_counts);
    int* rank   = (int*)(ws + o_rank);
    int* rowptr = (int*)(ws + o_rowptr);
    int* bsums  = (int*)(ws + o_bsums);
    int* col    = (int*)(ws + o_col);
    __half* h1  = (__half*)(ws + o_h1);
    float* hout = (float*)(ws + o_hout);
    __half* h2  = (__half*)(ws + o_h2);
    _Float16* w1f = (_Float16*)(ws + o_w1f);
    int* perm   = (int*)(ws + o_perm);
    int* dbins  = (int*)(ws + o_dbins);
    int* dstart = (int*)(ws + o_dstart);
    int* dfill  = (int*)(ws + o_dfill);
    float* ald1 = (float*)(ws + o_ald1);
    float* ard1 = (float*)(ws + o_ard1);
    float* ald2 = (float*)(ws + o_ald2);
    float* ard2 = (float*)(ws + o_ard2);

    hipLaunchKernelGGL(prep_k, dim3(NBLK), dim3(256), 0, stream,
                       (const unsigned*)ei, flag, counts, dbins, W1, w1f);
    hipLaunchKernelGGL(countrank_k, dim3((N_EDGES + 255) / 256), dim3(256), 0, stream,
                       ei, flag, counts, rank);
    hipLaunchKernelGGL(histscan1_k, dim3(NBLK + NSCAN), dim3(256), 0, stream,
                       counts, dbins, rowptr, bsums);
    hipLaunchKernelGGL(hscan_scan3_k, dim3(1 + NSCAN), dim3(256), 0, stream,
                       dbins, dstart, dfill, rowptr, bsums, col);
    hipLaunchKernelGGL(hscat_scat2_k, dim3(NBLK + NSCAT), dim3(256), 0, stream,
                       counts, dstart, dfill, perm, ei, flag, rowptr, rank, col);
    hipLaunchKernelGGL(gemm1_k, dim3((N_NODES + 63) / 64), dim3(256), 0, stream,
                       x, w1f, attl1, attr1, h1, ald1, ard1);
    hipLaunchKernelGGL(attn1_k, dim3((N_NODES * 8 + 255) / 256), dim3(256), 0, stream,
                       h1, rowptr, col, ald1, ard1, b1, perm, hout);
    hipLaunchKernelGGL(gemm2_k, dim3((N_NODES + 31) / 32), dim3(256), 0, stream,
                       hout, W2, attl2, attr2, (__half2*)h2, ald2, ard2);
    hipLaunchKernelGGL(attn2_k, dim3((N_NODES * 8 + 255) / 256), dim3(256), 0, stream,
                       h2, rowptr, col, ald2, ard2, b2, perm, out);
}